// Round 4
// baseline (152.478 us; speedup 1.0000x reference)
//
#include <hip/hip_runtime.h>
#include <math.h>

#define B 1024
#define C 100000
#define D 64
#define TC 256                  // classes per block (chunk)
#define NCH 391                 // ceil(C/TC); NCH*TC = 100096
#define NPADROWS (NCH * TC)
#define CPAD (NPADROWS - C)     // 96 zero pad rows
#define NP NCH                  // s-partials per row (one per chunk)
#define L2E 1.4426950408889634f

typedef __attribute__((ext_vector_type(8))) short short8;
typedef __attribute__((ext_vector_type(4))) float f32x4;

// ws byte layout:
//   [0, B*NP*4)       : s-partials float [row][chunk]   (~1.6 MB)
//   WS_CW2 (+4KB)     : cw2[row] = -2*||x_row||*log2e
//   WS_XBF (+128KB)   : xs as bf16 [B][64]
#define WS_PART 0
#define WS_CW2  ((size_t)B * NP * 4)
#define WS_XBF  (WS_CW2 + B * 4)

#define GLB(p) ((const __attribute__((address_space(1))) void*)(p))
#define LDS(p) ((__attribute__((address_space(3))) void*)(p))

static __device__ __forceinline__ unsigned short f2bf(float f) {
    unsigned u = __float_as_uint(f);
    return (unsigned short)((u + 0x7fffu + ((u >> 16) & 1u)) >> 16);  // RNE
}
static __device__ __forceinline__ float bf_round(float f) {
    return __uint_as_float(((unsigned)f2bf(f)) << 16);
}
static __device__ __forceinline__ float fexp2(float x) {
#if __has_builtin(__builtin_amdgcn_exp2f)
    return __builtin_amdgcn_exp2f(x);
#else
    return __expf(x * 0.6931471805599453f);
#endif
}

// ---- tiny prep: xs -> bf16 + cw2 (0.4 MB of traffic) ----
__global__ __launch_bounds__(256) void proxynca_prepx(
    const float* __restrict__ xs, unsigned short* __restrict__ Xbf,
    float* __restrict__ cw2)
{
    const int t = threadIdx.x;
    const int rl = t >> 4, f4 = t & 15;
    const int row = blockIdx.x * 16 + rl;
    const float4 v = *(const float4*)(xs + (size_t)row * D + f4 * 4);
    float ss = v.x*v.x + v.y*v.y + v.z*v.z + v.w*v.w;
    ss += __shfl_xor(ss, 1); ss += __shfl_xor(ss, 2);
    ss += __shfl_xor(ss, 4); ss += __shfl_xor(ss, 8);
    ushort4 w;
    w.x = f2bf(v.x); w.y = f2bf(v.y); w.z = f2bf(v.z); w.w = f2bf(v.w);
    *(ushort4*)(Xbf + (size_t)row * D + f4 * 4) = w;
    if (f4 == 0) cw2[row] = -2.0f * sqrtf(ss) * L2E;
}

// ---- main: per-chunk in-LDS normalization + 4 row-tiles of MFMA+exp ----
__global__ __launch_bounds__(512, 4) void proxynca_main(
    const float* __restrict__ proxies, const unsigned short* __restrict__ Xbf,
    const float* __restrict__ cw2v, float* __restrict__ partial)
{
    __shared__ __align__(16) unsigned short Bsh[TC * 64];      // 32 KB, swizzled
    __shared__ __align__(16) unsigned short Ash[2][128 * 64];  // 2 x 16 KB
    __shared__ float crow[512];
    __shared__ __align__(16) float scratch[128][4];

    const int t = threadIdx.x;                 // 0..511
    const int lane = t & 63;
    const int wv = t >> 6;                     // 0..7
    const int rh = blockIdx.x;                 // 0..1  (row half)
    const int ct = blockIdx.y;                 // 0..390
    const int rbase = rh * 512;

    const unsigned short* Asrc = Xbf + (size_t)rbase * D;

    // prefetch A tile 0 (source-XOR-swizzled so LDS(row,p)=global(row,p^row&7))
    #pragma unroll
    for (int j = 0; j < 2; ++j) {
        int c = (j * 8 + wv) * 64 + lane;
        int row = c >> 3, q = c & 7;
        int sc = (row << 3) | (q ^ (row & 7));
        __builtin_amdgcn_global_load_lds(GLB(Asrc + sc * 8),
            LDS(&Ash[0][(j * 8 + wv) * 512]), 16, 0, 0);
    }

    // normalize this block's 256-class chunk straight into LDS (bf16, swizzled)
    #pragma unroll
    for (int i = 0; i < 8; ++i) {
        int idx = i * 512 + t;
        int r = idx >> 4, f4 = idx & 15;       // r: 0..255
        int gc = ct * TC + r;
        float4 v = make_float4(0.f, 0.f, 0.f, 0.f);
        if (gc < C) v = *(const float4*)(proxies + (size_t)gc * D + f4 * 4);
        float ss = v.x*v.x + v.y*v.y + v.z*v.z + v.w*v.w;
        ss += __shfl_xor(ss, 1); ss += __shfl_xor(ss, 2);
        ss += __shfl_xor(ss, 4); ss += __shfl_xor(ss, 8);
        float rn = 1.0f / fmaxf(sqrtf(ss), 1e-12f);
        ushort4 w;
        w.x = f2bf(v.x * rn); w.y = f2bf(v.y * rn);
        w.z = f2bf(v.z * rn); w.w = f2bf(v.w * rn);
        int q = f4 >> 1, h = f4 & 1;
        int p = q ^ (r & 7);
        *(ushort4*)(Bsh + (size_t)((r * 8 + p) * 8 + h * 4)) = w;
    }
    crow[t] = cw2v[rbase + t];
    __syncthreads();                            // tile0 + Bsh + crow visible

    const int quad = lane >> 4, sixt = lane & 15;
    const int mg = wv >> 2, ng = wv & 3;

    // B fragments held in registers across the row-tile loop
    short8 bfr[4][2];
    #pragma unroll
    for (int ns = 0; ns < 4; ++ns) {
        int cl = ng * 64 + ns * 16 + sixt;
        int sw = cl & 7;
        bfr[ns][0] = *(const short8*)(Bsh + (size_t)(((cl << 3) | (quad ^ sw)) * 8));
        bfr[ns][1] = *(const short8*)(Bsh + (size_t)(((cl << 3) | ((4 + quad) ^ sw)) * 8));
    }

    for (int rt = 0; rt < 4; ++rt) {
        // prefetch next A tile into the other buffer
        if (rt < 3) {
            const unsigned short* An = Asrc + (size_t)(rt + 1) * 128 * D;
            #pragma unroll
            for (int j = 0; j < 2; ++j) {
                int c = (j * 8 + wv) * 64 + lane;
                int row = c >> 3, q = c & 7;
                int sc = (row << 3) | (q ^ (row & 7));
                __builtin_amdgcn_global_load_lds(GLB(An + sc * 8),
                    LDS(&Ash[(rt + 1) & 1][(j * 8 + wv) * 512]), 16, 0, 0);
            }
        }

        const unsigned short* Ab = Ash[rt & 1];
        short8 af[4][2];
        #pragma unroll
        for (int ms = 0; ms < 4; ++ms) {
            int rowL = mg * 64 + ms * 16 + sixt;
            int sw = rowL & 7;
            af[ms][0] = *(const short8*)(Ab + (size_t)(((rowL << 3) | (quad ^ sw)) * 8));
            af[ms][1] = *(const short8*)(Ab + (size_t)(((rowL << 3) | ((4 + quad) ^ sw)) * 8));
        }
        float cw[4][4];
        #pragma unroll
        for (int ms = 0; ms < 4; ++ms)
            #pragma unroll
            for (int rg = 0; rg < 4; ++rg)
                cw[ms][rg] = crow[rt * 128 + mg * 64 + ms * 16 + quad * 4 + rg];

        float s_acc[4][4];
        #pragma unroll
        for (int ms = 0; ms < 4; ++ms)
            #pragma unroll
            for (int rg = 0; rg < 4; ++rg) s_acc[ms][rg] = 0.f;

        #pragma unroll
        for (int ns = 0; ns < 4; ++ns)
            #pragma unroll
            for (int ms = 0; ms < 4; ++ms) {
                f32x4 acc = {0.f, 0.f, 0.f, 0.f};
                acc = __builtin_amdgcn_mfma_f32_16x16x32_bf16(af[ms][0], bfr[ns][0], acc, 0, 0, 0);
                acc = __builtin_amdgcn_mfma_f32_16x16x32_bf16(af[ms][1], bfr[ns][1], acc, 0, 0, 0);
                #pragma unroll
                for (int rg = 0; rg < 4; ++rg)
                    s_acc[ms][rg] += fexp2(fmaf(2.0f * L2E, acc[rg], cw[ms][rg]));
            }

        // 16-lane column reduce, then cross-wave (ng) combine via LDS
        #pragma unroll
        for (int ms = 0; ms < 4; ++ms)
            #pragma unroll
            for (int rg = 0; rg < 4; ++rg) {
                float s = s_acc[ms][rg];
                s += __shfl_xor(s, 1); s += __shfl_xor(s, 2);
                s += __shfl_xor(s, 4); s += __shfl_xor(s, 8);
                if (sixt == 0)
                    scratch[mg * 64 + ms * 16 + quad * 4 + rg][ng] = s;
            }
        __syncthreads();                        // scratch visible (+drains prefetch)
        if (t < 128) {
            float4 s4 = *(const float4*)scratch[t];
            partial[(size_t)(rbase + rt * 128 + t) * NP + ct] = s4.x + s4.y + s4.z + s4.w;
        }
        __syncthreads();                        // scratch free; next tile visible
    }
}

// ---- reduce + final mean (atomicAdd into zeroed d_out) ----
__global__ __launch_bounds__(256) void proxynca_reduce(
    const float* __restrict__ xs, const int* __restrict__ ys,
    const float* __restrict__ proxies, const float* __restrict__ partial,
    float* __restrict__ out)
{
    __shared__ float acc4[4];
    const int lane = threadIdx.x & 63;
    const int w = threadIdx.x >> 6;
    const int row = blockIdx.x * 4 + w;

    float x = xs[(size_t)row * D + lane];
    int y = ys[row];
    float p = proxies[(size_t)y * D + lane];

    float xx = x * x, pp = p * p;
    #pragma unroll
    for (int off = 1; off < 64; off <<= 1) {
        xx += __shfl_xor(xx, off);
        pp += __shfl_xor(pp, off);
    }
    float nx = sqrtf(xx);
    float rn = 1.0f / fmaxf(sqrtf(pp), 1e-12f);
    float ph = p * rn;

    float xp = x * ph;                       // exact fp32 dot for d_pos
    float xpb = bf_round(x) * bf_round(ph);  // bf16-matched dot for s subtraction
    #pragma unroll
    for (int off = 1; off < 64; off <<= 1) {
        xp  += __shfl_xor(xp, off);
        xpb += __shfl_xor(xpb, off);
    }

    float s = 0.f;
    for (int j = lane; j < NP; j += 64) s += partial[(size_t)row * NP + j];
    #pragma unroll
    for (int off = 1; off < 64; off <<= 1) s += __shfl_xor(s, off);

    if (lane == 0) {
        float cw2r = -2.0f * nx * L2E;
        float e_pos = fexp2(fmaf(2.0f * L2E, xpb, cw2r));   // positive class term
        float e_pad = fexp2(cw2r);                          // each zero pad row
        float s_neg = s - e_pos - (float)CPAD * e_pad;
        acc4[w] = 2.0f * (nx - xp) + logf(s_neg);
    }
    __syncthreads();
    if (threadIdx.x == 0) {
        float v = acc4[0] + acc4[1] + acc4[2] + acc4[3];
        atomicAdd(out, v * (1.0f / (float)B));
    }
}

extern "C" void kernel_launch(void* const* d_in, const int* in_sizes, int n_in,
                              void* d_out, int out_size, void* d_ws, size_t ws_size,
                              hipStream_t stream)
{
    const float* xs      = (const float*)d_in[0];
    const int*   ys      = (const int*)d_in[1];
    const float* proxies = (const float*)d_in[2];
    char* ws = (char*)d_ws;
    float* partial = (float*)(ws + WS_PART);
    float* cw2     = (float*)(ws + WS_CW2);
    unsigned short* Xbf = (unsigned short*)(ws + WS_XBF);
    float* out = (float*)d_out;

    hipMemsetAsync(out, 0, sizeof(float), stream);
    proxynca_prepx<<<B / 16, 256, 0, stream>>>(xs, Xbf, cw2);
    dim3 gridA(2, NCH);
    proxynca_main<<<gridA, 512, 0, stream>>>(proxies, Xbf, cw2, partial);
    proxynca_reduce<<<B / 4, 256, 0, stream>>>(xs, ys, proxies, partial, out);
}

// Round 5
// 132.606 us; speedup vs baseline: 1.1499x; 1.1499x over previous
//
#include <hip/hip_runtime.h>
#include <math.h>

#define B 1024
#define C 100000
#define D 64
#define TC 128                  // classes per chunk
#define NCH 782                 // ceil(C/TC); NCH*TC = 100096
#define NPADROWS (NCH * TC)
#define CPAD (NPADROWS - C)     // 96 zero pad rows
#define NP NCH
#define L2E 1.4426950408889634f

typedef __attribute__((ext_vector_type(8))) short short8;
typedef __attribute__((ext_vector_type(4))) float f32x4;

// ws byte layout:
//   [0, NCH*B*4)      : s-partials float [chunk][row]  (~3.2 MB, transposed!)
//   WS_CW2 (+4KB)     : cw2[row] = -2*||x_row||*log2e
//   WS_XBF (+128KB)   : xs as bf16 [B][64]
#define WS_PART 0
#define WS_CW2  ((size_t)NCH * B * 4)
#define WS_XBF  (WS_CW2 + B * 4)

#define GLB(p) ((const __attribute__((address_space(1))) void*)(p))
#define LDS(p) ((__attribute__((address_space(3))) void*)(p))

static __device__ __forceinline__ unsigned short f2bf(float f) {
    unsigned u = __float_as_uint(f);
    return (unsigned short)((u + 0x7fffu + ((u >> 16) & 1u)) >> 16);  // RNE
}
static __device__ __forceinline__ float bf_round(float f) {
    return __uint_as_float(((unsigned)f2bf(f)) << 16);
}
static __device__ __forceinline__ float fexp2(float x) {
#if __has_builtin(__builtin_amdgcn_exp2f)
    return __builtin_amdgcn_exp2f(x);
#else
    return __expf(x * 0.6931471805599453f);
#endif
}

// ---- tiny prep: xs -> bf16 + cw2 ----
__global__ __launch_bounds__(256) void proxynca_prepx(
    const float* __restrict__ xs, unsigned short* __restrict__ Xbf,
    float* __restrict__ cw2)
{
    const int t = threadIdx.x;
    const int rl = t >> 4, f4 = t & 15;
    const int row = blockIdx.x * 16 + rl;
    const float4 v = *(const float4*)(xs + (size_t)row * D + f4 * 4);
    float ss = v.x*v.x + v.y*v.y + v.z*v.z + v.w*v.w;
    ss += __shfl_xor(ss, 1); ss += __shfl_xor(ss, 2);
    ss += __shfl_xor(ss, 4); ss += __shfl_xor(ss, 8);
    ushort4 w;
    w.x = f2bf(v.x); w.y = f2bf(v.y); w.z = f2bf(v.z); w.w = f2bf(v.w);
    *(ushort4*)(Xbf + (size_t)row * D + f4 * 4) = w;
    if (f4 == 0) cw2[row] = -2.0f * sqrtf(ss) * L2E;
}

// ---- main: 256 rows x 128 classes per block; fused normalize + MFMA + exp ----
__global__ __launch_bounds__(512, 4) void proxynca_main(
    const float* __restrict__ proxies, const unsigned short* __restrict__ Xbf,
    const float* __restrict__ cw2v, float* __restrict__ partial)
{
    __shared__ __align__(16) unsigned short Ash[256 * 64];   // 32 KB, swizzled
    __shared__ __align__(16) unsigned short Bsh[TC * 64];    // 16 KB, swizzled
    __shared__ float crow[256];
    __shared__ __align__(8) float scratch[256][2];

    const int t = threadIdx.x;                 // 0..511
    const int lane = t & 63;
    const int wv = t >> 6;                     // 0..7
    const int rg = blockIdx.x;                 // 0..3  (row group of 256)
    const int ct = blockIdx.y;                 // 0..781
    const int rbase = rg * 256;

    const unsigned short* Asrc = Xbf + (size_t)rbase * D;

    // stage A via DMA (source-XOR-swizzled: LDS(row,p) = global(row, p^(row&7)))
    #pragma unroll
    for (int j = 0; j < 4; ++j) {
        int c = (j * 8 + wv) * 64 + lane;
        int row = c >> 3, q = c & 7;
        int sc = (row << 3) | (q ^ (row & 7));
        __builtin_amdgcn_global_load_lds(GLB(Asrc + sc * 8),
            LDS(Ash + (size_t)(j * 8 + wv) * 512), 16, 0, 0);
    }

    // normalize this block's 128-class chunk straight into LDS (bf16, swizzled)
    #pragma unroll
    for (int i = 0; i < 4; ++i) {
        int idx = i * 512 + t;
        int r = idx >> 4, f4 = idx & 15;       // r: 0..127
        int gc = ct * TC + r;
        float4 v = make_float4(0.f, 0.f, 0.f, 0.f);
        if (gc < C) v = *(const float4*)(proxies + (size_t)gc * D + f4 * 4);
        float ss = v.x*v.x + v.y*v.y + v.z*v.z + v.w*v.w;
        ss += __shfl_xor(ss, 1); ss += __shfl_xor(ss, 2);
        ss += __shfl_xor(ss, 4); ss += __shfl_xor(ss, 8);
        float rn = 1.0f / fmaxf(sqrtf(ss), 1e-12f);
        ushort4 w;
        w.x = f2bf(v.x * rn); w.y = f2bf(v.y * rn);
        w.z = f2bf(v.z * rn); w.w = f2bf(v.w * rn);
        int p = (f4 >> 1) ^ (r & 7);
        *(ushort4*)(Bsh + (size_t)((r * 8 + p) * 8 + (f4 & 1) * 4)) = w;
    }
    if (t < 256) crow[t] = cw2v[rbase + t];
    __syncthreads();                            // A tile + Bsh + crow visible

    const int quad = lane >> 4, sixt = lane & 15;
    const int mg = wv >> 1;                     // 0..3 : 64-row group
    const int ng = wv & 1;                      // 0..1 : 64-class group

    short8 bfr[4][2];
    #pragma unroll
    for (int ns = 0; ns < 4; ++ns) {
        int cl = ng * 64 + ns * 16 + sixt;
        int sw = cl & 7;
        bfr[ns][0] = *(const short8*)(Bsh + (size_t)(((cl << 3) | (quad ^ sw)) * 8));
        bfr[ns][1] = *(const short8*)(Bsh + (size_t)(((cl << 3) | ((4 + quad) ^ sw)) * 8));
    }
    short8 af[4][2];
    #pragma unroll
    for (int ms = 0; ms < 4; ++ms) {
        int rowL = mg * 64 + ms * 16 + sixt;
        int sw = rowL & 7;
        af[ms][0] = *(const short8*)(Ash + (size_t)(((rowL << 3) | (quad ^ sw)) * 8));
        af[ms][1] = *(const short8*)(Ash + (size_t)(((rowL << 3) | ((4 + quad) ^ sw)) * 8));
    }
    float cw[4][4];
    #pragma unroll
    for (int ms = 0; ms < 4; ++ms)
        #pragma unroll
        for (int rgi = 0; rgi < 4; ++rgi)
            cw[ms][rgi] = crow[mg * 64 + ms * 16 + quad * 4 + rgi];

    float s_acc[4][4];
    #pragma unroll
    for (int ms = 0; ms < 4; ++ms)
        #pragma unroll
        for (int rgi = 0; rgi < 4; ++rgi) s_acc[ms][rgi] = 0.f;

    #pragma unroll
    for (int ns = 0; ns < 4; ++ns)
        #pragma unroll
        for (int ms = 0; ms < 4; ++ms) {
            f32x4 acc = {0.f, 0.f, 0.f, 0.f};
            acc = __builtin_amdgcn_mfma_f32_16x16x32_bf16(af[ms][0], bfr[ns][0], acc, 0, 0, 0);
            acc = __builtin_amdgcn_mfma_f32_16x16x32_bf16(af[ms][1], bfr[ns][1], acc, 0, 0, 0);
            #pragma unroll
            for (int rgi = 0; rgi < 4; ++rgi)
                s_acc[ms][rgi] += fexp2(fmaf(2.0f * L2E, acc[rgi], cw[ms][rgi]));
        }

    // 16-lane column reduce -> scratch[row][ng]
    #pragma unroll
    for (int ms = 0; ms < 4; ++ms)
        #pragma unroll
        for (int rgi = 0; rgi < 4; ++rgi) {
            float s = s_acc[ms][rgi];
            s += __shfl_xor(s, 1); s += __shfl_xor(s, 2);
            s += __shfl_xor(s, 4); s += __shfl_xor(s, 8);
            if (sixt == 0)
                scratch[mg * 64 + ms * 16 + quad * 4 + rgi][ng] = s;
        }
    __syncthreads();
    // coalesced 1 KB store: each line written fully by this block only
    if (t < 256)
        partial[(size_t)ct * B + rbase + t] = scratch[t][0] + scratch[t][1];
}

// ---- reduce + final mean (atomicAdd into zeroed d_out) ----
__global__ __launch_bounds__(256) void proxynca_reduce(
    const float* __restrict__ xs, const int* __restrict__ ys,
    const float* __restrict__ proxies, const float* __restrict__ partial,
    float* __restrict__ out)
{
    __shared__ float acc4[4];
    const int lane = threadIdx.x & 63;
    const int w = threadIdx.x >> 6;
    const int row = blockIdx.x * 4 + w;

    float x = xs[(size_t)row * D + lane];
    int y = ys[row];
    float p = proxies[(size_t)y * D + lane];

    float xx = x * x, pp = p * p;
    #pragma unroll
    for (int off = 1; off < 64; off <<= 1) {
        xx += __shfl_xor(xx, off);
        pp += __shfl_xor(pp, off);
    }
    float nx = sqrtf(xx);
    float rn = 1.0f / fmaxf(sqrtf(pp), 1e-12f);
    float ph = p * rn;

    float xp = x * ph;                       // exact fp32 dot for d_pos
    float xpb = bf_round(x) * bf_round(ph);  // bf16-matched dot for s subtraction
    #pragma unroll
    for (int off = 1; off < 64; off <<= 1) {
        xp  += __shfl_xor(xp, off);
        xpb += __shfl_xor(xpb, off);
    }

    float s = 0.f;
    for (int j = lane; j < NP; j += 64) s += partial[(size_t)j * B + row];
    #pragma unroll
    for (int off = 1; off < 64; off <<= 1) s += __shfl_xor(s, off);

    if (lane == 0) {
        float cw2r = -2.0f * nx * L2E;
        float e_pos = fexp2(fmaf(2.0f * L2E, xpb, cw2r));   // positive class term
        float e_pad = fexp2(cw2r);                          // each zero pad row
        float s_neg = s - e_pos - (float)CPAD * e_pad;
        acc4[w] = 2.0f * (nx - xp) + logf(s_neg);
    }
    __syncthreads();
    if (threadIdx.x == 0) {
        float v = acc4[0] + acc4[1] + acc4[2] + acc4[3];
        atomicAdd(out, v * (1.0f / (float)B));
    }
}

extern "C" void kernel_launch(void* const* d_in, const int* in_sizes, int n_in,
                              void* d_out, int out_size, void* d_ws, size_t ws_size,
                              hipStream_t stream)
{
    const float* xs      = (const float*)d_in[0];
    const int*   ys      = (const int*)d_in[1];
    const float* proxies = (const float*)d_in[2];
    char* ws = (char*)d_ws;
    float* partial = (float*)(ws + WS_PART);
    float* cw2     = (float*)(ws + WS_CW2);
    unsigned short* Xbf = (unsigned short*)(ws + WS_XBF);
    float* out = (float*)d_out;

    hipMemsetAsync(out, 0, sizeof(float), stream);
    proxynca_prepx<<<B / 16, 256, 0, stream>>>(xs, Xbf, cw2);
    dim3 gridA(4, NCH);
    proxynca_main<<<gridA, 512, 0, stream>>>(proxies, Xbf, cw2, partial);
    proxynca_reduce<<<B / 4, 256, 0, stream>>>(xs, ys, proxies, partial, out);
}